// Round 4
// baseline (492.952 us; speedup 1.0000x reference)
//
#include <hip/hip_runtime.h>
#include <hip/hip_fp16.h>

// HashGrid encode: N=524288, L=16, F=2, T=2^19.
// R4 structure:
//  - Pre-pass: [L,F,T] fp32 -> [L,T] __half2 in d_ws (4 B/entry).
//  - Main: one thread = one point x one level-octet (8 levels).
//    g = blk*256+tid in [0, 2N); p = g>>1, octet = g&1.
//    -> 4096 blocks (4x R3) for occupancy / memory-level parallelism;
//    64 independent gathers per thread across 8 separate accumulators.
//    Adjacent lanes (same point, octets 0/1) write the two 64 B halves of
//    one 128 B out line within the same wave -> full-line writes.

#define HG_L     16
#define HG_LOG_T 19
#define HG_T     (1u << HG_LOG_T)
#define HG_N     524288u

__global__ __launch_bounds__(256) void interleave_fp16(
    const float* __restrict__ hm,   // [L, F, T]
    __half2* __restrict__ ws)       // [L, T]
{
    const unsigned u = (blockIdx.x * 256u + threadIdx.x) * 4u; // entry base, %4==0
    const unsigned l = u >> HG_LOG_T;
    const unsigned t = u & (HG_T - 1u);
    const float* base = hm + (size_t)l * (2u * HG_T);
    const float4 a = *reinterpret_cast<const float4*>(base + t);          // f=0
    const float4 b = *reinterpret_cast<const float4*>(base + HG_T + t);   // f=1
    __half2 h0 = __floats2half2_rn(a.x, b.x);
    __half2 h1 = __floats2half2_rn(a.y, b.y);
    __half2 h2 = __floats2half2_rn(a.z, b.z);
    __half2 h3 = __floats2half2_rn(a.w, b.w);
    uint4 o;
    o.x = *reinterpret_cast<unsigned*>(&h0);
    o.y = *reinterpret_cast<unsigned*>(&h1);
    o.z = *reinterpret_cast<unsigned*>(&h2);
    o.w = *reinterpret_cast<unsigned*>(&h3);
    *reinterpret_cast<uint4*>(ws + u) = o;
}

__device__ __forceinline__ float2 level_encode(
    float px, float py, float pz, float res,
    const __half2* __restrict__ tab)
{
    const float xs0 = px * res, xs1 = py * res, xs2 = pz * res;
    const float fl0 = floorf(xs0), fl1 = floorf(xs1), fl2 = floorf(xs2);
    const float fr0 = xs0 - fl0, fr1 = xs1 - fl1, fr2 = xs2 - fl2;
    const unsigned x0 = (unsigned)fl0;
    const unsigned x1 = (unsigned)fl1;
    const unsigned x2 = (unsigned)fl2;

    const unsigned P1 = 2654435761u, P2 = 805459861u;
    const unsigned hx0 = x0,          hx1 = x0 + 1u;
    const unsigned hy0 = x1 * P1,     hy1 = hy0 + P1;
    const unsigned hz0 = x2 * P2,     hz1 = hz0 + P2;

    const float w0x = 1.0f - fr0, w1x = fr0;
    const float w0y = 1.0f - fr1, w1y = fr1;
    const float w0z = 1.0f - fr2, w1z = fr2;

    float ax = 0.0f, ay = 0.0f;
#pragma unroll
    for (int c = 0; c < 8; ++c) {
        const unsigned dx = (c >> 2) & 1, dy = (c >> 1) & 1, dz = c & 1;
        const unsigned idx = ((dx ? hx1 : hx0) ^ (dy ? hy1 : hy0) ^ (dz ? hz1 : hz0))
                             & (HG_T - 1u);
        const float w = (dx ? w1x : w0x) * (dy ? w1y : w0y) * (dz ? w1z : w0z);
        const float2 v = __half22float2(tab[idx]);
        ax += w * v.x;
        ay += w * v.y;
    }
    return make_float2(ax, ay);
}

__global__ __launch_bounds__(256) void hg_main(
    const float*   __restrict__ x,          // [N, 3]
    const __half2* __restrict__ wst,        // [L, T]
    const float*   __restrict__ resolution, // [L]
    float*         __restrict__ out)        // [N, 32]
{
    const unsigned g     = blockIdx.x * 256u + threadIdx.x;  // [0, 2N)
    const unsigned p     = g >> 1;
    const unsigned octet = g & 1u;
    const unsigned lbase = octet * 8u;

    const float px = x[p * 3 + 0];
    const float py = x[p * 3 + 1];
    const float pz = x[p * 3 + 2];

    float2 acc[8];
#pragma unroll
    for (int lo = 0; lo < 8; ++lo) {
        const unsigned l = lbase + lo;
        const float res = resolution[l];
        const __half2* tab = wst + (size_t)l * HG_T;
        acc[lo] = level_encode(px, py, pz, res, tab);
    }

    // thread writes its own 64 B chunk: out[p*32 + octet*16 .. +16)
    float4* d = reinterpret_cast<float4*>(out + (size_t)p * 32u + lbase * 2u);
    d[0] = make_float4(acc[0].x, acc[0].y, acc[1].x, acc[1].y);
    d[1] = make_float4(acc[2].x, acc[2].y, acc[3].x, acc[3].y);
    d[2] = make_float4(acc[4].x, acc[4].y, acc[5].x, acc[5].y);
    d[3] = make_float4(acc[6].x, acc[6].y, acc[7].x, acc[7].y);
}

extern "C" void kernel_launch(void* const* d_in, const int* in_sizes, int n_in,
                              void* d_out, int out_size, void* d_ws, size_t ws_size,
                              hipStream_t stream) {
    const float* x          = (const float*)d_in[0];
    const float* hashmap    = (const float*)d_in[1];
    const float* resolution = (const float*)d_in[2];
    float* out              = (float*)d_out;

    __half2* wst = (__half2*)d_ws;  // needs 32 MiB; harness ws is sized generously

    hipLaunchKernelGGL(interleave_fp16,
                       dim3((HG_L * HG_T / 4u) / 256u), dim3(256), 0, stream,
                       hashmap, wst);

    const unsigned grid_main = (2u * HG_N) / 256u;  // 4096 blocks
    hipLaunchKernelGGL(hg_main, dim3(grid_main), dim3(256), 0, stream,
                       x, wst, resolution, out);
}

// Round 5
// 348.685 us; speedup vs baseline: 1.4137x; 1.4137x over previous
//
#include <hip/hip_runtime.h>
#include <hip/hip_fp16.h>

// HashGrid encode: N=524288, L=16, F=2, T=2^19.
// R5: reduce divergent lane-gathers 128 -> ~86 per point.
//  - Hashed levels (5..15): dim-0 prime is 1, so idx(dx=1) = idx(dx=0)^1 when
//    x0 is even. Interleaved half2 table already stores entries (2m,2m+1)
//    contiguously -> one aligned 8B uint2 load covers both x-corners.
//    4 unconditional pair-loads + 4 predicated loads (only odd-x0 lanes).
//  - Dense levels (0..4): duplicated lattice latD[i]=(v(x),v(x+1)) in ws
//    (2.65 MB, L2-resident) -> guaranteed 4 aligned 8B loads, no branch.
//  - Thread structure from R3 (fastest so far): 2 points x 16 levels/thread,
//    1024 blocks, 8-level chunks, 64B stores.

#define HG_L     16
#define HG_LOG_T 19
#define HG_T     (1u << HG_LOG_T)
#define HG_N     524288u
#define HP1      2654435761u
#define HP2      805459861u

// dense levels: resolution = {16,22,30,42,58} -> S = res+1
#define DS0 17u
#define DS1 23u
#define DS2 31u
#define DS3 43u
#define DS4 59u
#define DOFF0 0u
#define DOFF1 4913u       // 17^3
#define DOFF2 17080u      // +23^3
#define DOFF3 46871u      // +31^3
#define DOFF4 126378u     // +43^3
#define DTOTAL 331757u    // +59^3
#define TAB_U2 (HG_L * (HG_T / 2u))   // uint2 slots of hashed table = 4194304

__global__ __launch_bounds__(256) void interleave_fp16(
    const float* __restrict__ hm,   // [L, F, T]
    __half2* __restrict__ ws)       // [L, T]
{
    const unsigned u = (blockIdx.x * 256u + threadIdx.x) * 4u;
    const unsigned l = u >> HG_LOG_T;
    const unsigned t = u & (HG_T - 1u);
    const float* base = hm + (size_t)l * (2u * HG_T);
    const float4 a = *reinterpret_cast<const float4*>(base + t);          // f=0
    const float4 b = *reinterpret_cast<const float4*>(base + HG_T + t);   // f=1
    __half2 h0 = __floats2half2_rn(a.x, b.x);
    __half2 h1 = __floats2half2_rn(a.y, b.y);
    __half2 h2 = __floats2half2_rn(a.z, b.z);
    __half2 h3 = __floats2half2_rn(a.w, b.w);
    uint4 o;
    o.x = *reinterpret_cast<unsigned*>(&h0);
    o.y = *reinterpret_cast<unsigned*>(&h1);
    o.z = *reinterpret_cast<unsigned*>(&h2);
    o.w = *reinterpret_cast<unsigned*>(&h3);
    *reinterpret_cast<uint4*>(ws + u) = o;
}

__global__ __launch_bounds__(256) void build_lattice(
    const float* __restrict__ hm,   // [L, F, T]
    uint2* __restrict__ latD)       // [DTOTAL] duplicated pairs
{
    const unsigned l = blockIdx.y;  // 0..4
    unsigned S, off;
    switch (l) {
        case 0: S = DS0; off = DOFF0; break;
        case 1: S = DS1; off = DOFF1; break;
        case 2: S = DS2; off = DOFF2; break;
        case 3: S = DS3; off = DOFF3; break;
        default: S = DS4; off = DOFF4; break;
    }
    const unsigned i = blockIdx.x * 256u + threadIdx.x;
    if (i >= S * S * S) return;
    const unsigned x  = i % S;
    const unsigned t1 = i / S;
    const unsigned y  = t1 % S;
    const unsigned z  = t1 / S;
    const unsigned hyz = y * HP1 ^ z * HP2;
    const unsigned i0 = (hyz ^ x) & (HG_T - 1u);
    const unsigned i1 = (hyz ^ (x + 1u)) & (HG_T - 1u);
    const float* b0 = hm + (size_t)l * (2u * HG_T);
    __half2 v0 = __floats2half2_rn(b0[i0], b0[i0 + HG_T]);
    __half2 v1 = __floats2half2_rn(b0[i1], b0[i1 + HG_T]);
    uint2 o;
    o.x = *reinterpret_cast<unsigned*>(&v0);
    o.y = *reinterpret_cast<unsigned*>(&v1);
    latD[off + i] = o;
}

__device__ __forceinline__ float2 hfv(unsigned raw) {
    return __half22float2(*reinterpret_cast<const __half2*>(&raw));
}

template <unsigned S, unsigned OFF>
__device__ __forceinline__ float2 enc_dense(
    float px, float py, float pz, float res,
    const uint2* __restrict__ latD)
{
    const float xs0 = px * res, xs1 = py * res, xs2 = pz * res;
    const float fl0 = floorf(xs0), fl1 = floorf(xs1), fl2 = floorf(xs2);
    const float fr0 = xs0 - fl0, fr1 = xs1 - fl1, fr2 = xs2 - fl2;
    const unsigned x0 = (unsigned)fl0;
    const unsigned y0 = (unsigned)fl1;
    const unsigned z0 = (unsigned)fl2;

    const unsigned i = (z0 * S + y0) * S + x0 + OFF;
    const uint2 q00 = latD[i];               // (x0,y0,z0), (x0+1,y0,z0)
    const uint2 q10 = latD[i + S];           // y0+1
    const uint2 q01 = latD[i + S * S];       // z0+1
    const uint2 q11 = latD[i + S * S + S];   // y0+1, z0+1

    const float w0x = 1.0f - fr0, w1x = fr0;
    const float w00 = (1.0f - fr1) * (1.0f - fr2);
    const float w10 = fr1 * (1.0f - fr2);
    const float w01 = (1.0f - fr1) * fr2;
    const float w11 = fr1 * fr2;

    const float2 a00 = hfv(q00.x), b00 = hfv(q00.y);
    const float2 a10 = hfv(q10.x), b10 = hfv(q10.y);
    const float2 a01 = hfv(q01.x), b01 = hfv(q01.y);
    const float2 a11 = hfv(q11.x), b11 = hfv(q11.y);

    float ax = 0.0f, ay = 0.0f;
    ax += w00 * (w0x * a00.x + w1x * b00.x);
    ay += w00 * (w0x * a00.y + w1x * b00.y);
    ax += w10 * (w0x * a10.x + w1x * b10.x);
    ay += w10 * (w0x * a10.y + w1x * b10.y);
    ax += w01 * (w0x * a01.x + w1x * b01.x);
    ay += w01 * (w0x * a01.y + w1x * b01.y);
    ax += w11 * (w0x * a11.x + w1x * b11.x);
    ay += w11 * (w0x * a11.y + w1x * b11.y);
    return make_float2(ax, ay);
}

__device__ __forceinline__ float2 enc_hash(
    float px, float py, float pz, float res,
    const uint2* __restrict__ tab2)   // level's table as aligned pairs
{
    const float xs0 = px * res, xs1 = py * res, xs2 = pz * res;
    const float fl0 = floorf(xs0), fl1 = floorf(xs1), fl2 = floorf(xs2);
    const float fr0 = xs0 - fl0, fr1 = xs1 - fl1, fr2 = xs2 - fl2;
    const unsigned x0 = (unsigned)fl0;
    const unsigned y0 = (unsigned)fl1;
    const unsigned z0 = (unsigned)fl2;
    const unsigned M = HG_T - 1u;

    const unsigned hy0 = y0 * HP1, hy1 = hy0 + HP1;
    const unsigned hz0 = z0 * HP2, hz1 = hz0 + HP2;
    const unsigned H0 = hy0 ^ hz0;
    const unsigned H1 = hy1 ^ hz0;
    const unsigned H2 = hy0 ^ hz1;
    const unsigned H3 = hy1 ^ hz1;

    unsigned r0[4], r1[4];
    {
        const unsigned i0 = (H0 ^ x0) & M; const uint2 q = tab2[i0 >> 1];
        r0[0] = (i0 & 1u) ? q.y : q.x;  r1[0] = (i0 & 1u) ? q.x : q.y;
    }
    {
        const unsigned i0 = (H1 ^ x0) & M; const uint2 q = tab2[i0 >> 1];
        r0[1] = (i0 & 1u) ? q.y : q.x;  r1[1] = (i0 & 1u) ? q.x : q.y;
    }
    {
        const unsigned i0 = (H2 ^ x0) & M; const uint2 q = tab2[i0 >> 1];
        r0[2] = (i0 & 1u) ? q.y : q.x;  r1[2] = (i0 & 1u) ? q.x : q.y;
    }
    {
        const unsigned i0 = (H3 ^ x0) & M; const uint2 q = tab2[i0 >> 1];
        r0[3] = (i0 & 1u) ? q.y : q.x;  r1[3] = (i0 & 1u) ? q.x : q.y;
    }
    // odd x0: partner halves are wrong; reload the dx=1 corners (masked lanes)
    if (x0 & 1u) {
        const unsigned xp = x0 + 1u;
        {
            const unsigned i1 = (H0 ^ xp) & M; const uint2 q = tab2[i1 >> 1];
            r1[0] = (i1 & 1u) ? q.y : q.x;
        }
        {
            const unsigned i1 = (H1 ^ xp) & M; const uint2 q = tab2[i1 >> 1];
            r1[1] = (i1 & 1u) ? q.y : q.x;
        }
        {
            const unsigned i1 = (H2 ^ xp) & M; const uint2 q = tab2[i1 >> 1];
            r1[2] = (i1 & 1u) ? q.y : q.x;
        }
        {
            const unsigned i1 = (H3 ^ xp) & M; const uint2 q = tab2[i1 >> 1];
            r1[3] = (i1 & 1u) ? q.y : q.x;
        }
    }

    const float w0x = 1.0f - fr0, w1x = fr0;
    const float w00 = (1.0f - fr1) * (1.0f - fr2);
    const float w10 = fr1 * (1.0f - fr2);
    const float w01 = (1.0f - fr1) * fr2;
    const float w11 = fr1 * fr2;

    float ax = 0.0f, ay = 0.0f;
    {
        const float2 v0 = hfv(r0[0]), v1 = hfv(r1[0]);
        ax += w00 * (w0x * v0.x + w1x * v1.x);
        ay += w00 * (w0x * v0.y + w1x * v1.y);
    }
    {
        const float2 v0 = hfv(r0[1]), v1 = hfv(r1[1]);
        ax += w10 * (w0x * v0.x + w1x * v1.x);
        ay += w10 * (w0x * v0.y + w1x * v1.y);
    }
    {
        const float2 v0 = hfv(r0[2]), v1 = hfv(r1[2]);
        ax += w01 * (w0x * v0.x + w1x * v1.x);
        ay += w01 * (w0x * v0.y + w1x * v1.y);
    }
    {
        const float2 v0 = hfv(r0[3]), v1 = hfv(r1[3]);
        ax += w11 * (w0x * v0.x + w1x * v1.x);
        ay += w11 * (w0x * v0.y + w1x * v1.y);
    }
    return make_float2(ax, ay);
}

__global__ __launch_bounds__(256) void hg_main(
    const float* __restrict__ x,          // [N, 3]
    const uint2* __restrict__ tab2,       // [L*T/2] hashed pair table
    const uint2* __restrict__ latD,       // [DTOTAL] dense lattices
    const float* __restrict__ resolution, // [L]
    float*       __restrict__ out)        // [N, 32]
{
    const unsigned tid = threadIdx.x;
    const unsigned p0  = blockIdx.x * 512u + tid;   // 1024 blocks
    const unsigned p1  = p0 + 256u;

    const float ax0 = x[p0 * 3 + 0], ay0 = x[p0 * 3 + 1], az0 = x[p0 * 3 + 2];
    const float ax1 = x[p1 * 3 + 0], ay1 = x[p1 * 3 + 1], az1 = x[p1 * 3 + 2];

    // ---- chunk 0: levels 0..7 (dense 0..4, hashed 5..7) ----
    {
        float2 A0[8], A1[8];
        A0[0] = enc_dense<DS0, DOFF0>(ax0, ay0, az0, resolution[0], latD);
        A1[0] = enc_dense<DS0, DOFF0>(ax1, ay1, az1, resolution[0], latD);
        A0[1] = enc_dense<DS1, DOFF1>(ax0, ay0, az0, resolution[1], latD);
        A1[1] = enc_dense<DS1, DOFF1>(ax1, ay1, az1, resolution[1], latD);
        A0[2] = enc_dense<DS2, DOFF2>(ax0, ay0, az0, resolution[2], latD);
        A1[2] = enc_dense<DS2, DOFF2>(ax1, ay1, az1, resolution[2], latD);
        A0[3] = enc_dense<DS3, DOFF3>(ax0, ay0, az0, resolution[3], latD);
        A1[3] = enc_dense<DS3, DOFF3>(ax1, ay1, az1, resolution[3], latD);
        A0[4] = enc_dense<DS4, DOFF4>(ax0, ay0, az0, resolution[4], latD);
        A1[4] = enc_dense<DS4, DOFF4>(ax1, ay1, az1, resolution[4], latD);
#pragma unroll
        for (int l = 5; l < 8; ++l) {
            const float res = resolution[l];
            const uint2* tl = tab2 + (size_t)l * (HG_T / 2u);
            A0[l] = enc_hash(ax0, ay0, az0, res, tl);
            A1[l] = enc_hash(ax1, ay1, az1, res, tl);
        }
        float4* d0 = reinterpret_cast<float4*>(out + (size_t)p0 * 32u);
        float4* d1 = reinterpret_cast<float4*>(out + (size_t)p1 * 32u);
        d0[0] = make_float4(A0[0].x, A0[0].y, A0[1].x, A0[1].y);
        d0[1] = make_float4(A0[2].x, A0[2].y, A0[3].x, A0[3].y);
        d0[2] = make_float4(A0[4].x, A0[4].y, A0[5].x, A0[5].y);
        d0[3] = make_float4(A0[6].x, A0[6].y, A0[7].x, A0[7].y);
        d1[0] = make_float4(A1[0].x, A1[0].y, A1[1].x, A1[1].y);
        d1[1] = make_float4(A1[2].x, A1[2].y, A1[3].x, A1[3].y);
        d1[2] = make_float4(A1[4].x, A1[4].y, A1[5].x, A1[5].y);
        d1[3] = make_float4(A1[6].x, A1[6].y, A1[7].x, A1[7].y);
    }
    // ---- chunk 1: levels 8..15 (all hashed) ----
    {
        float2 A0[8], A1[8];
#pragma unroll
        for (int l = 8; l < 16; ++l) {
            const float res = resolution[l];
            const uint2* tl = tab2 + (size_t)l * (HG_T / 2u);
            A0[l - 8] = enc_hash(ax0, ay0, az0, res, tl);
            A1[l - 8] = enc_hash(ax1, ay1, az1, res, tl);
        }
        float4* d0 = reinterpret_cast<float4*>(out + (size_t)p0 * 32u + 16u);
        float4* d1 = reinterpret_cast<float4*>(out + (size_t)p1 * 32u + 16u);
        d0[0] = make_float4(A0[0].x, A0[0].y, A0[1].x, A0[1].y);
        d0[1] = make_float4(A0[2].x, A0[2].y, A0[3].x, A0[3].y);
        d0[2] = make_float4(A0[4].x, A0[4].y, A0[5].x, A0[5].y);
        d0[3] = make_float4(A0[6].x, A0[6].y, A0[7].x, A0[7].y);
        d1[0] = make_float4(A1[0].x, A1[0].y, A1[1].x, A1[1].y);
        d1[1] = make_float4(A1[2].x, A1[2].y, A1[3].x, A1[3].y);
        d1[2] = make_float4(A1[4].x, A1[4].y, A1[5].x, A1[5].y);
        d1[3] = make_float4(A1[6].x, A1[6].y, A1[7].x, A1[7].y);
    }
}

extern "C" void kernel_launch(void* const* d_in, const int* in_sizes, int n_in,
                              void* d_out, int out_size, void* d_ws, size_t ws_size,
                              hipStream_t stream) {
    const float* x          = (const float*)d_in[0];
    const float* hashmap    = (const float*)d_in[1];
    const float* resolution = (const float*)d_in[2];
    float* out              = (float*)d_out;

    __half2* wst  = (__half2*)d_ws;                     // 32 MiB hashed table
    uint2*   latD = (uint2*)d_ws + TAB_U2;              // 2.65 MB lattices

    hipLaunchKernelGGL(interleave_fp16,
                       dim3((HG_L * HG_T / 4u) / 256u), dim3(256), 0, stream,
                       hashmap, wst);
    hipLaunchKernelGGL(build_lattice,
                       dim3((DS4 * DS4 * DS4 + 255u) / 256u, 5), dim3(256), 0, stream,
                       hashmap, latD);

    hipLaunchKernelGGL(hg_main, dim3(HG_N / 512u), dim3(256), 0, stream,
                       x, (const uint2*)d_ws, latD, resolution, out);
}

// Round 6
// 338.039 us; speedup vs baseline: 1.4583x; 1.0315x over previous
//
#include <hip/hip_runtime.h>
#include <hip/hip_fp16.h>

// HashGrid encode: N=524288, L=16, F=2, T=2^19.
// R6: lane-request reduction 86 -> 72 per point.
//  - Dense levels 0..5 (res 16,22,30,42,58,80): quad-packed lattice
//    quad[cell] = {v(x,y), v(x+1,y), v(x,y+1), v(x+1,y+1)} as 4x half2 (16 B)
//    -> 2 aligned 16 B loads per level (z0 and z0+1 slabs). 13.8 MB in ws.
//  - Hashed levels 6..15: interleaved half2 pair-table; dim-0 prime = 1 so
//    even x0 gets both x-corners from one aligned 8 B load; odd-x0 lanes
//    (≈50%) issue 4 extra masked loads. avg 6 requests/level.
//  - Schedule (best so far, R3/R5): 2 points x 16 levels per thread,
//    1024 blocks, 8-level register chunks, 64 B float4 stores.

#define HG_L     16
#define HG_LOG_T 19
#define HG_T     (1u << HG_LOG_T)
#define HG_N     524288u
#define HP1      2654435761u
#define HP2      805459861u

// dense levels 0..5: resolution {16,22,30,42,58,80} -> S = res+1
#define DS0 17u
#define DS1 23u
#define DS2 31u
#define DS3 43u
#define DS4 59u
#define DS5 81u
#define DOFF0 0u
#define DOFF1 4913u      // +17^3
#define DOFF2 17080u     // +23^3
#define DOFF3 46871u     // +31^3
#define DOFF4 126378u    // +43^3
#define DOFF5 331757u    // +59^3
#define DTOTAL 863198u   // +81^3  (cells; 16 B each = 13.81 MB)

#define TAB_BYTES ((size_t)HG_L * HG_T * 4u)   // 32 MiB hashed region in ws

__global__ __launch_bounds__(256) void interleave_fp16(
    const float* __restrict__ hm,   // [L, F, T]
    __half2* __restrict__ ws)       // [L, T] (only levels 6..15 written)
{
    const unsigned u = 6u * HG_T + (blockIdx.x * 256u + threadIdx.x) * 4u;
    const unsigned l = u >> HG_LOG_T;
    const unsigned t = u & (HG_T - 1u);
    const float* base = hm + (size_t)l * (2u * HG_T);
    const float4 a = *reinterpret_cast<const float4*>(base + t);          // f=0
    const float4 b = *reinterpret_cast<const float4*>(base + HG_T + t);   // f=1
    __half2 h0 = __floats2half2_rn(a.x, b.x);
    __half2 h1 = __floats2half2_rn(a.y, b.y);
    __half2 h2 = __floats2half2_rn(a.z, b.z);
    __half2 h3 = __floats2half2_rn(a.w, b.w);
    uint4 o;
    o.x = *reinterpret_cast<unsigned*>(&h0);
    o.y = *reinterpret_cast<unsigned*>(&h1);
    o.z = *reinterpret_cast<unsigned*>(&h2);
    o.w = *reinterpret_cast<unsigned*>(&h3);
    *reinterpret_cast<uint4*>(ws + u) = o;
}

__device__ __forceinline__ unsigned pack_h2(float f0, float f1) {
    __half2 h = __floats2half2_rn(f0, f1);
    return *reinterpret_cast<unsigned*>(&h);
}

__global__ __launch_bounds__(256) void build_quad(
    const float* __restrict__ hm,   // [L, F, T]
    uint4* __restrict__ quad)       // [DTOTAL]
{
    const unsigned l = blockIdx.y;  // 0..5
    unsigned S, off;
    switch (l) {
        case 0: S = DS0; off = DOFF0; break;
        case 1: S = DS1; off = DOFF1; break;
        case 2: S = DS2; off = DOFF2; break;
        case 3: S = DS3; off = DOFF3; break;
        case 4: S = DS4; off = DOFF4; break;
        default: S = DS5; off = DOFF5; break;
    }
    const unsigned i = blockIdx.x * 256u + threadIdx.x;
    if (i >= S * S * S) return;
    const unsigned x  = i % S;
    const unsigned t1 = i / S;
    const unsigned y  = t1 % S;
    const unsigned z  = t1 / S;
    const unsigned M = HG_T - 1u;
    const unsigned hz = z * HP2;
    const unsigned hy0 = y * HP1, hy1 = hy0 + HP1;
    const unsigned i00 = (hy0 ^ hz ^ x) & M;
    const unsigned i10 = (hy0 ^ hz ^ (x + 1u)) & M;
    const unsigned i01 = (hy1 ^ hz ^ x) & M;
    const unsigned i11 = (hy1 ^ hz ^ (x + 1u)) & M;
    const float* b0 = hm + (size_t)l * (2u * HG_T);
    uint4 o;
    o.x = pack_h2(b0[i00], b0[i00 + HG_T]);
    o.y = pack_h2(b0[i10], b0[i10 + HG_T]);
    o.z = pack_h2(b0[i01], b0[i01 + HG_T]);
    o.w = pack_h2(b0[i11], b0[i11 + HG_T]);
    quad[off + i] = o;
}

__device__ __forceinline__ float2 hfv(unsigned raw) {
    return __half22float2(*reinterpret_cast<const __half2*>(&raw));
}

template <unsigned S, unsigned OFF>
__device__ __forceinline__ float2 enc_dense(
    float px, float py, float pz, float res,
    const uint4* __restrict__ quad)
{
    const float xs0 = px * res, xs1 = py * res, xs2 = pz * res;
    const float fl0 = floorf(xs0), fl1 = floorf(xs1), fl2 = floorf(xs2);
    const float fr0 = xs0 - fl0, fr1 = xs1 - fl1, fr2 = xs2 - fl2;
    const unsigned x0 = (unsigned)fl0;
    const unsigned y0 = (unsigned)fl1;
    const unsigned z0 = (unsigned)fl2;

    const unsigned i = (z0 * S + y0) * S + x0 + OFF;
    const uint4 q0 = quad[i];             // z0 slab: v00,v10,v01,v11
    const uint4 q1 = quad[i + S * S];     // z0+1 slab

    const float w0x = 1.0f - fr0, w1x = fr0;
    const float w0y = 1.0f - fr1, w1y = fr1;
    const float w0z = 1.0f - fr2, w1z = fr2;

    const float2 a00 = hfv(q0.x), a10 = hfv(q0.y), a01 = hfv(q0.z), a11 = hfv(q0.w);
    const float2 b00 = hfv(q1.x), b10 = hfv(q1.y), b01 = hfv(q1.z), b11 = hfv(q1.w);

    // bilinear in (x,y) per z-slab, then lerp z
    const float s0x = w0y * (w0x * a00.x + w1x * a10.x) + w1y * (w0x * a01.x + w1x * a11.x);
    const float s0y = w0y * (w0x * a00.y + w1x * a10.y) + w1y * (w0x * a01.y + w1x * a11.y);
    const float s1x = w0y * (w0x * b00.x + w1x * b10.x) + w1y * (w0x * b01.x + w1x * b11.x);
    const float s1y = w0y * (w0x * b00.y + w1x * b10.y) + w1y * (w0x * b01.y + w1x * b11.y);

    return make_float2(w0z * s0x + w1z * s1x, w0z * s0y + w1z * s1y);
}

__device__ __forceinline__ float2 enc_hash(
    float px, float py, float pz, float res,
    const uint2* __restrict__ tab2)   // level's table as aligned pairs
{
    const float xs0 = px * res, xs1 = py * res, xs2 = pz * res;
    const float fl0 = floorf(xs0), fl1 = floorf(xs1), fl2 = floorf(xs2);
    const float fr0 = xs0 - fl0, fr1 = xs1 - fl1, fr2 = xs2 - fl2;
    const unsigned x0 = (unsigned)fl0;
    const unsigned y0 = (unsigned)fl1;
    const unsigned z0 = (unsigned)fl2;
    const unsigned M = HG_T - 1u;

    const unsigned hy0 = y0 * HP1, hy1 = hy0 + HP1;
    const unsigned hz0 = z0 * HP2, hz1 = hz0 + HP2;
    const unsigned H0 = hy0 ^ hz0;
    const unsigned H1 = hy1 ^ hz0;
    const unsigned H2 = hy0 ^ hz1;
    const unsigned H3 = hy1 ^ hz1;

    unsigned r0[4], r1[4];
    {
        const unsigned i0 = (H0 ^ x0) & M; const uint2 q = tab2[i0 >> 1];
        r0[0] = (i0 & 1u) ? q.y : q.x;  r1[0] = (i0 & 1u) ? q.x : q.y;
    }
    {
        const unsigned i0 = (H1 ^ x0) & M; const uint2 q = tab2[i0 >> 1];
        r0[1] = (i0 & 1u) ? q.y : q.x;  r1[1] = (i0 & 1u) ? q.x : q.y;
    }
    {
        const unsigned i0 = (H2 ^ x0) & M; const uint2 q = tab2[i0 >> 1];
        r0[2] = (i0 & 1u) ? q.y : q.x;  r1[2] = (i0 & 1u) ? q.x : q.y;
    }
    {
        const unsigned i0 = (H3 ^ x0) & M; const uint2 q = tab2[i0 >> 1];
        r0[3] = (i0 & 1u) ? q.y : q.x;  r1[3] = (i0 & 1u) ? q.x : q.y;
    }
    if (x0 & 1u) {   // partner corners wrong for odd x0: reload (masked lanes)
        const unsigned xp = x0 + 1u;
        { const unsigned i1 = (H0 ^ xp) & M; const uint2 q = tab2[i1 >> 1];
          r1[0] = (i1 & 1u) ? q.y : q.x; }
        { const unsigned i1 = (H1 ^ xp) & M; const uint2 q = tab2[i1 >> 1];
          r1[1] = (i1 & 1u) ? q.y : q.x; }
        { const unsigned i1 = (H2 ^ xp) & M; const uint2 q = tab2[i1 >> 1];
          r1[2] = (i1 & 1u) ? q.y : q.x; }
        { const unsigned i1 = (H3 ^ xp) & M; const uint2 q = tab2[i1 >> 1];
          r1[3] = (i1 & 1u) ? q.y : q.x; }
    }

    const float w0x = 1.0f - fr0, w1x = fr0;
    const float w00 = (1.0f - fr1) * (1.0f - fr2);
    const float w10 = fr1 * (1.0f - fr2);
    const float w01 = (1.0f - fr1) * fr2;
    const float w11 = fr1 * fr2;

    float ax = 0.0f, ay = 0.0f;
    { const float2 v0 = hfv(r0[0]), v1 = hfv(r1[0]);
      ax += w00 * (w0x * v0.x + w1x * v1.x);
      ay += w00 * (w0x * v0.y + w1x * v1.y); }
    { const float2 v0 = hfv(r0[1]), v1 = hfv(r1[1]);
      ax += w10 * (w0x * v0.x + w1x * v1.x);
      ay += w10 * (w0x * v0.y + w1x * v1.y); }
    { const float2 v0 = hfv(r0[2]), v1 = hfv(r1[2]);
      ax += w01 * (w0x * v0.x + w1x * v1.x);
      ay += w01 * (w0x * v0.y + w1x * v1.y); }
    { const float2 v0 = hfv(r0[3]), v1 = hfv(r1[3]);
      ax += w11 * (w0x * v0.x + w1x * v1.x);
      ay += w11 * (w0x * v0.y + w1x * v1.y); }
    return make_float2(ax, ay);
}

__global__ __launch_bounds__(256) void hg_main(
    const float* __restrict__ x,          // [N, 3]
    const uint2* __restrict__ tab2,       // hashed pair table [L*T/2]
    const uint4* __restrict__ quad,       // dense quad lattices [DTOTAL]
    const float* __restrict__ resolution, // [L]
    float*       __restrict__ out)        // [N, 32]
{
    const unsigned tid = threadIdx.x;
    const unsigned p0  = blockIdx.x * 512u + tid;   // 1024 blocks
    const unsigned p1  = p0 + 256u;

    const float ax0 = x[p0 * 3 + 0], ay0 = x[p0 * 3 + 1], az0 = x[p0 * 3 + 2];
    const float ax1 = x[p1 * 3 + 0], ay1 = x[p1 * 3 + 1], az1 = x[p1 * 3 + 2];

    // ---- chunk 0: levels 0..7 (dense 0..5, hashed 6..7) ----
    {
        float2 A0[8], A1[8];
        A0[0] = enc_dense<DS0, DOFF0>(ax0, ay0, az0, resolution[0], quad);
        A1[0] = enc_dense<DS0, DOFF0>(ax1, ay1, az1, resolution[0], quad);
        A0[1] = enc_dense<DS1, DOFF1>(ax0, ay0, az0, resolution[1], quad);
        A1[1] = enc_dense<DS1, DOFF1>(ax1, ay1, az1, resolution[1], quad);
        A0[2] = enc_dense<DS2, DOFF2>(ax0, ay0, az0, resolution[2], quad);
        A1[2] = enc_dense<DS2, DOFF2>(ax1, ay1, az1, resolution[2], quad);
        A0[3] = enc_dense<DS3, DOFF3>(ax0, ay0, az0, resolution[3], quad);
        A1[3] = enc_dense<DS3, DOFF3>(ax1, ay1, az1, resolution[3], quad);
        A0[4] = enc_dense<DS4, DOFF4>(ax0, ay0, az0, resolution[4], quad);
        A1[4] = enc_dense<DS4, DOFF4>(ax1, ay1, az1, resolution[4], quad);
        A0[5] = enc_dense<DS5, DOFF5>(ax0, ay0, az0, resolution[5], quad);
        A1[5] = enc_dense<DS5, DOFF5>(ax1, ay1, az1, resolution[5], quad);
#pragma unroll
        for (int l = 6; l < 8; ++l) {
            const float res = resolution[l];
            const uint2* tl = tab2 + (size_t)l * (HG_T / 2u);
            A0[l] = enc_hash(ax0, ay0, az0, res, tl);
            A1[l] = enc_hash(ax1, ay1, az1, res, tl);
        }
        float4* d0 = reinterpret_cast<float4*>(out + (size_t)p0 * 32u);
        float4* d1 = reinterpret_cast<float4*>(out + (size_t)p1 * 32u);
        d0[0] = make_float4(A0[0].x, A0[0].y, A0[1].x, A0[1].y);
        d0[1] = make_float4(A0[2].x, A0[2].y, A0[3].x, A0[3].y);
        d0[2] = make_float4(A0[4].x, A0[4].y, A0[5].x, A0[5].y);
        d0[3] = make_float4(A0[6].x, A0[6].y, A0[7].x, A0[7].y);
        d1[0] = make_float4(A1[0].x, A1[0].y, A1[1].x, A1[1].y);
        d1[1] = make_float4(A1[2].x, A1[2].y, A1[3].x, A1[3].y);
        d1[2] = make_float4(A1[4].x, A1[4].y, A1[5].x, A1[5].y);
        d1[3] = make_float4(A1[6].x, A1[6].y, A1[7].x, A1[7].y);
    }
    // ---- chunk 1: levels 8..15 (all hashed) ----
    {
        float2 A0[8], A1[8];
#pragma unroll
        for (int l = 8; l < 16; ++l) {
            const float res = resolution[l];
            const uint2* tl = tab2 + (size_t)l * (HG_T / 2u);
            A0[l - 8] = enc_hash(ax0, ay0, az0, res, tl);
            A1[l - 8] = enc_hash(ax1, ay1, az1, res, tl);
        }
        float4* d0 = reinterpret_cast<float4*>(out + (size_t)p0 * 32u + 16u);
        float4* d1 = reinterpret_cast<float4*>(out + (size_t)p1 * 32u + 16u);
        d0[0] = make_float4(A0[0].x, A0[0].y, A0[1].x, A0[1].y);
        d0[1] = make_float4(A0[2].x, A0[2].y, A0[3].x, A0[3].y);
        d0[2] = make_float4(A0[4].x, A0[4].y, A0[5].x, A0[5].y);
        d0[3] = make_float4(A0[6].x, A0[6].y, A0[7].x, A0[7].y);
        d1[0] = make_float4(A1[0].x, A1[0].y, A1[1].x, A1[1].y);
        d1[1] = make_float4(A1[2].x, A1[2].y, A1[3].x, A1[3].y);
        d1[2] = make_float4(A1[4].x, A1[4].y, A1[5].x, A1[5].y);
        d1[3] = make_float4(A1[6].x, A1[6].y, A1[7].x, A1[7].y);
    }
}

extern "C" void kernel_launch(void* const* d_in, const int* in_sizes, int n_in,
                              void* d_out, int out_size, void* d_ws, size_t ws_size,
                              hipStream_t stream) {
    const float* x          = (const float*)d_in[0];
    const float* hashmap    = (const float*)d_in[1];
    const float* resolution = (const float*)d_in[2];
    float* out              = (float*)d_out;

    __half2* wst  = (__half2*)d_ws;                              // 32 MiB hashed region
    uint4*   quad = (uint4*)((char*)d_ws + TAB_BYTES);           // 13.8 MB quads

    // hashed slices for levels 6..15 only: 10*T entries / 4 per thread
    hipLaunchKernelGGL(interleave_fp16,
                       dim3((10u * HG_T / 4u) / 256u), dim3(256), 0, stream,
                       hashmap, wst);
    hipLaunchKernelGGL(build_quad,
                       dim3((DS5 * DS5 * DS5 + 255u) / 256u, 6), dim3(256), 0, stream,
                       hashmap, quad);

    hipLaunchKernelGGL(hg_main, dim3(HG_N / 512u), dim3(256), 0, stream,
                       x, (const uint2*)d_ws, quad, resolution, out);
}